// Round 6
// baseline (5349.364 us; speedup 1.0000x reference)
//
#include <hip/hip_runtime.h>
#include <math.h>

#define T_ 32
#define B_ 16
#define NA 18
#define P_ 540   // 27*20

typedef __attribute__((ext_vector_type(8)))  short short8;
typedef __attribute__((ext_vector_type(16))) float f32x16;

__device__ __forceinline__ float sigm(float x){ return 1.0f/(1.0f+expf(-x)); }
__device__ __forceinline__ unsigned short f2bf(float f){
    unsigned u = __float_as_uint(f);
    u += 0x7fff + ((u>>16)&1u);
    return (unsigned short)(u>>16);
}
__device__ __forceinline__ float bfu(unsigned short u){ return __uint_as_float(((unsigned)u)<<16); }
__device__ __forceinline__ float BFLO(unsigned x){ return __uint_as_float(x<<16); }
__device__ __forceinline__ float BFHI(unsigned x){ return __uint_as_float(x & 0xffff0000u); }

// ---------------- conv1 block (512 thr): frame n, output rows oh..oh+1 -> c1buf slot
// c1buf layout: [slot 3][16 n][32 oc][56][42] bf16 (halo pre-zeroed once)
__device__ __forceinline__ void conv1_block(const float* __restrict__ frame,
                                            const float* __restrict__ w,
                                            const float* __restrict__ bias,
                                            unsigned short* __restrict__ c1buf,
                                            int n, int slot, int oh, int tid, char* smraw){
    float* tile = (float*)smraw;  // 3ch * 12rows * 168cols = 24.2 KB
    const float* fb = frame + (size_t)n*3*210*160;
    for (int s = tid; s < 6048; s += 512){
        int col = s % 168;
        int row = (s/168) % 12;
        int ic  = s / 2016;
        int iy = oh*4 - 1 + row;
        int ix = col - 2;
        float v = 0.f;
        if (iy >= 0 && iy < 210 && ix >= 0 && ix < 160) v = fb[ic*33600 + iy*160 + ix];
        tile[s] = v;
    }
    __syncthreads();
    int oc = tid & 31, grp = (tid >> 5) & 7, rsel = tid >> 8;
    float acc[5] = {0.f,0.f,0.f,0.f,0.f};
    const float* wb = w + oc*192;
    for (int ic=0; ic<3; ++ic){
        #pragma unroll
        for (int kh=0; kh<8; ++kh){
            const float* wr = wb + ic*64 + kh*8;
            float4 w0 = *((const float4*)wr);
            float4 w1 = *((const float4*)(wr+4));
            const float* row = tile + ic*2016 + (kh + 4*rsel)*168 + grp*20;
            float r[24];
            *((float4*)(r+ 0)) = *((const float4*)(row+ 0));
            *((float4*)(r+ 4)) = *((const float4*)(row+ 4));
            *((float4*)(r+ 8)) = *((const float4*)(row+ 8));
            *((float4*)(r+12)) = *((const float4*)(row+12));
            *((float4*)(r+16)) = *((const float4*)(row+16));
            *((float4*)(r+20)) = *((const float4*)(row+20));
            #pragma unroll
            for (int o=0;o<5;++o){
                acc[o] += r[o*4+0]*w0.x + r[o*4+1]*w0.y + r[o*4+2]*w0.z + r[o*4+3]*w0.w
                        + r[o*4+4]*w1.x + r[o*4+5]*w1.y + r[o*4+6]*w1.z + r[o*4+7]*w1.w;
            }
        }
    }
    float bi = bias[oc];
    unsigned short* ob = c1buf + ((size_t)((slot*16 + (n & 15))*32 + oc)*56 + oh+2+rsel)*42 + 1;
    #pragma unroll
    for (int o=0;o<5;++o) ob[grp*5+o] = f2bf(acc[o] + bi);
}

// ---------------- conv2 block (512 thr, 8 waves): c1buf slot -> xre[s][540 pos][64 oc]
__device__ __forceinline__ void c2_block(const unsigned short* __restrict__ c1buf,
                                         const unsigned short* __restrict__ apack2,
                                         const float* __restrict__ bias,
                                         unsigned short* __restrict__ xre,
                                         int s, int slot, int n0, int tid, char* smraw){
    unsigned short (*p2)[3072] = (unsigned short (*)[3072])smraw;   // 12 KB
    float* bsm = (float*)(smraw + 12288);
    int wave = tid >> 6, lane = tid & 63;
    int khalf = (lane>>5) << 3;
    if (tid < 64) bsm[tid] = bias[tid];
    const unsigned short* cb = c1buf + (size_t)(slot*16 + (s & 15))*32*2352;

    int soff[4], swaddr[4];
    #pragma unroll
    for (int q=0;q<4;++q){
        int idx = q*512 + tid;
        int n = idx & 127, k = idx >> 7;
        int p = n0 + n; if (p > 539) p = 539;
        soff[q] = ((p/20)*2 + (k>>2))*42 + (p%20)*2 + (k&3);
        swaddr[q] = n*24 + k;
    }
    #pragma unroll
    for (int q=0;q<4;++q) p2[0][swaddr[q]] = cb[soff[q]];
    unsigned short rv[4];
    #pragma unroll
    for (int q=0;q<4;++q) rv[q] = cb[2352 + soff[q]];

    int mt = wave >> 2, nq = wave & 3;
    short8 acur = *((const short8*)(apack2 + ((size_t)mt*64 + lane)*8));
    short8 anxt;
    f32x16 acc;
    #pragma unroll
    for (int rg=0;rg<16;++rg) acc[rg] = 0.f;
    __syncthreads();

    for (int c=0; c<32; ++c){
        int buf = c & 1;
        if (c < 31){
            #pragma unroll
            for (int q=0;q<4;++q) p2[buf^1][swaddr[q]] = rv[q];
        }
        if (c < 30){
            const unsigned short* src = cb + (size_t)(c+2)*2352;
            #pragma unroll
            for (int q=0;q<4;++q) rv[q] = src[soff[q]];
        }
        if (c < 31) anxt = *((const short8*)(apack2 + ((size_t)((c+1)*2 + mt)*64 + lane)*8));
        {
            int n = nq*32 + (lane & 31);
            short8 bf = *((const short8*)(&p2[buf][n*24 + khalf]));
            acc = __builtin_amdgcn_mfma_f32_32x32x16_bf16(acur, bf, acc, 0, 0, 0);
        }
        acur = anxt;
        __syncthreads();
    }
    int pos = n0 + nq*32 + (lane & 31);
    if (pos < 540){
        unsigned short* op = xre + ((size_t)s*540 + pos)*64;
        #pragma unroll
        for (int rg=0; rg<16; ++rg){
            int oc = mt*32 + (rg & 3) + 8*(rg>>2) + 4*(lane>>5);
            op[oc] = f2bf(acc[rg] + bsm[oc]);
        }
    }
}

// ---------------- standalone prologue wrappers
__global__ __launch_bounds__(512) void conv1pro(const float* __restrict__ frame,
                                                const float* __restrict__ w,
                                                const float* __restrict__ bias,
                                                unsigned short* __restrict__ c1buf){
    __shared__ __align__(16) char sm[24576];
    int n = blockIdx.x/26, oh = (blockIdx.x%26)*2;
    conv1_block(frame, w, bias, c1buf, n, (n>>4)%3, oh, threadIdx.x, sm);
}
__global__ __launch_bounds__(512) void c2pro(const unsigned short* __restrict__ c1buf,
                                             const unsigned short* __restrict__ apack2,
                                             const float* __restrict__ bias,
                                             unsigned short* __restrict__ xre){
    __shared__ __align__(16) char sm[12544];
    c2_block(c1buf, apack2, bias, xre, blockIdx.x/5, 0, (blockIdx.x%5)*128, threadIdx.x, sm);
}

// ---------------- conv2 A-pack: cnn_w2 (64,32,4,4) -> apack2[32 ic][2 mt][64 lane][8] bf16
__global__ void apack2k(const float* __restrict__ w2, unsigned short* __restrict__ ap){
    int idx = blockIdx.x*256 + threadIdx.x;
    if (idx >= 32768) return;
    int j = idx & 7;
    int lane = (idx>>3) & 63;
    int mt = (idx>>9) & 1;
    int ic = idx >> 10;
    int k = ((lane>>5)<<3) + j;
    int oc = mt*32 + (lane & 31);
    ap[idx] = f2bf(w2[((oc*32 + ic)<<4) + k]);
}

// ---------------- spatial basis S[540][64] + transpose ST[64][540]
__global__ void sbasisk(float* __restrict__ S, float* __restrict__ ST){
    int idx = blockIdx.x*256 + threadIdx.x;
    if (idx >= P_*64) return;
    int s = idx & 63, p = idx >> 6;
    int y = p/20, x = p%20;
    int u = s >> 3, v = s & 7;
    double a  = cos((double)((y+1)*(u+1)) * M_PI / 27.0);
    double bb = cos((double)((x+1)*(v+1)) * M_PI / 20.0);
    float fv = (float)(a*bb);
    S[idx] = fv;
    ST[(size_t)s*540 + p] = fv;
}

// ---------------- weight pack x8: f32 [R][C] -> bf16 [(R+7)/8][C][8]  (pad rows -> 0)
__global__ void packw8k(const float* __restrict__ in, unsigned short* __restrict__ out, int R, int C){
    int idx = blockIdx.x*256 + threadIdx.x;
    int r8cnt = (R+7)>>3;
    if (idx >= r8cnt*C*8) return;
    int j = idx & 7;
    int rc = idx >> 3;
    int c = rc % C;
    int r = (rc / C)*8 + j;
    out[idx] = (r < R) ? f2bf(in[(size_t)r*C + c]) : (unsigned short)0;
}
// ---------------- weight pack x8 (transposed input): f32 [C][R] -> bf16 [(R+7)/8][C][8]
__global__ void packt8k(const float* __restrict__ in, unsigned short* __restrict__ out, int R, int C){
    int idx = blockIdx.x*256 + threadIdx.x;
    int r8cnt = (R+7)>>3;
    if (idx >= r8cnt*C*8) return;
    int j = idx & 7;
    int rc = idx >> 3;
    int c = rc % C;
    int r = (rc / C)*8 + j;
    out[idx] = (r < R) ? f2bf(in[(size_t)c*R + r]) : (unsigned short)0;
}

// ---------------- gates A-pack (tap-wise): lstm_w (512,192,3,3) ->
// ap[tap 9][chunk 12][16 mt][64 lane][8] bf16, K = 192 channels (no zero padding)
__global__ void apack9k(const float* __restrict__ lw, unsigned short* __restrict__ ap){
    int idx = blockIdx.x*256 + threadIdx.x;
    if (idx >= 884736) return;
    int j = idx & 7;
    int lane = (idx>>3) & 63;
    int mt = (idx>>9) & 15;
    int f  = idx >> 13;
    int tap = f / 12, c = f % 12;
    int ch = c*16 + ((lane>>5)<<3) + j;
    int oc = mt*32 + (lane & 31);
    ap[idx] = f2bf(lw[(size_t)oc*1728 + ch*9 + tap]);
}

// ---------------- pack conv_h0 fp32 [b][128][540] -> h0re bf16 [b][540 pos][128 ch]
__global__ void h0rek(const float* __restrict__ h0, unsigned short* __restrict__ h0re){
    int idx = blockIdx.x*256 + threadIdx.x;
    if (idx >= 16*128*540) return;
    int plane = idx / 540, p = idx % 540;
    int b = plane >> 7, c = plane & 127;
    h0re[((size_t)b*540 + p)*128 + c] = f2bf(h0[idx]);
}

// =====================================================================================
// gvck: ONE dispatch per t runs FOUR independent stages concurrently:
//   blocks 0..15   : core recurrence step t-1   (critical chain, scheduled first)
//   blocks 16..303 : vis ConvLSTM step t        (direct-global MFMA conv + pointwise)
//   blocks 304..719: conv1 chunk for frame t+2  (-> c1buf slot (t+2)%3)
//   blocks 720..799: conv2 chunk for frame t+1  (c1buf slot (t+1)%3 -> xre[t+1])
// All cross-stage dependencies span >=1 dispatch boundary -> stream-ordered, race-free.
// =====================================================================================
__global__ __launch_bounds__(512) void gvck(const float* __restrict__ frame,
                                            const float* __restrict__ cnn_w1,
                                            const float* __restrict__ cnn_b1,
                                            unsigned short* __restrict__ c1buf,
                                            const unsigned short* __restrict__ apack2,
                                            const float* __restrict__ cnn_b2,
                                            unsigned short* __restrict__ xre,
                                            const unsigned short* __restrict__ hrd,
                                            unsigned short* __restrict__ hwr,
                                            const unsigned short* __restrict__ h0re,
                                            const unsigned short* __restrict__ apack,
                                            const float* __restrict__ lb,
                                            const unsigned char* __restrict__ done,
                                            float* __restrict__ vh, float* __restrict__ vc,
                                            unsigned short* __restrict__ hreA,
                                            const float* __restrict__ S,
                                            const float* __restrict__ ST,
                                            const unsigned short* __restrict__ pq1, const float* __restrict__ qb1,
                                            const unsigned short* __restrict__ pq2, const float* __restrict__ qb2,
                                            const unsigned short* __restrict__ pq3, const float* __restrict__ qb3,
                                            const unsigned short* __restrict__ pa1, const float* __restrict__ ab1,
                                            const unsigned short* __restrict__ pa2, const float* __restrict__ ab2,
                                            const unsigned short* __restrict__ pih, const unsigned short* __restrict__ phh,
                                            const float* __restrict__ bih, const float* __restrict__ bhh,
                                            const float* __restrict__ reward, const int* __restrict__ lact,
                                            float* __restrict__ hsb, float* __restrict__ csb,
                                            float* __restrict__ outs,
                                            int t){
    __shared__ __align__(16) char smraw[65536];
    int bid = blockIdx.x;
    int tid = threadIdx.x;

    if (bid >= 720){
        int tp1 = t + 1; if (tp1 > 31) return;
        int idx = bid - 720;
        c2_block(c1buf, apack2, cnn_b2, xre, tp1*16 + idx/5, tp1%3, (idx%5)*128, tid, smraw);
        return;
    }
    if (bid >= 304){
        int tp2 = t + 2; if (tp2 > 31) return;
        int idx = bid - 304;
        conv1_block(frame, cnn_w1, cnn_b1, c1buf, tp2*16 + idx/26, tp2%3, (idx%26)*2, tid, smraw);
        return;
    }

    if (bid >= 16){
        // ---------------- vis ConvLSTM step t ----------------
        if (t >= T_) return;
        float* gsm = (float*)smraw;                    // [4][64][64] f32 (64 KB)
        int vb = bid - 16;
        int b  = vb % 16;
        int r  = vb / 16;
        int nb = r % 9;
        int mh = r / 9;
        int wave = tid >> 6, lane = tid & 63;
        int khalf = (lane>>5) << 3;
        int n0 = nb * 64;
        bool dn = done[t*B_ + b];

        const unsigned short* xb = xre + (size_t)(t*B_ + b)*540*64;
        const unsigned short* hp2 = (t==0) ? (h0re + (size_t)b*540*128)
                                           : (hrd  + (size_t)b*540*128);

        int mt = (wave>>1)*4 + mh*2 + (wave&1);

        int poff[2][9]; int vmask[2][9];
        #pragma unroll
        for (int jj=0;jj<2;++jj){
            int p = n0 + jj*32 + (lane & 31); if (p > 539) p = 539;
            int y = p/20, x = p%20;
            #pragma unroll
            for (int tap=0;tap<9;++tap){
                int dy = tap/3 - 1, dx = tap%3 - 1;
                int yy = y+dy, xx = x+dx;
                vmask[jj][tap] = ((unsigned)yy < 27u) && ((unsigned)xx < 20u);
                poff[jj][tap] = yy*20 + xx;
            }
        }
        const short8 z8 = {0,0,0,0,0,0,0,0};
        f32x16 acc[2];
        #pragma unroll
        for (int jj=0;jj<2;++jj)
            #pragma unroll
            for (int rg=0;rg<16;++rg) acc[jj][rg] = 0.f;

        for (int c=0;c<4;++c){
            int cho = c*16 + khalf;
            #pragma unroll
            for (int tap=0;tap<9;++tap){
                short8 af = *((const short8*)(apack + ((size_t)((tap*12+c)*16 + mt)*64 + lane)*8));
                short8 b0 = vmask[0][tap] ? *((const short8*)(xb + poff[0][tap]*64 + cho)) : z8;
                short8 b1 = vmask[1][tap] ? *((const short8*)(xb + poff[1][tap]*64 + cho)) : z8;
                acc[0] = __builtin_amdgcn_mfma_f32_32x32x16_bf16(af, b0, acc[0], 0, 0, 0);
                acc[1] = __builtin_amdgcn_mfma_f32_32x32x16_bf16(af, b1, acc[1], 0, 0, 0);
            }
        }
        if (!dn){
            for (int c=4;c<12;++c){
                int cho = (c-4)*16 + khalf;
                #pragma unroll
                for (int tap=0;tap<9;++tap){
                    short8 af = *((const short8*)(apack + ((size_t)((tap*12+c)*16 + mt)*64 + lane)*8));
                    short8 b0 = vmask[0][tap] ? *((const short8*)(hp2 + poff[0][tap]*128 + cho)) : z8;
                    short8 b1 = vmask[1][tap] ? *((const short8*)(hp2 + poff[1][tap]*128 + cho)) : z8;
                    acc[0] = __builtin_amdgcn_mfma_f32_32x32x16_bf16(af, b0, acc[0], 0, 0, 0);
                    acc[1] = __builtin_amdgcn_mfma_f32_32x32x16_bf16(af, b1, acc[1], 0, 0, 0);
                }
            }
        }

        int g8 = wave >> 1, ih = wave & 1;
        #pragma unroll
        for (int j=0;j<2;++j){
            int p_loc = j*32 + (lane & 31);
            #pragma unroll
            for (int rg=0; rg<16; ++rg){
                int c_loc = ih*32 + 4*(lane>>5) + (rg & 3) + 8*(rg>>2);
                gsm[g8*4096 + c_loc*64 + p_loc] = acc[j][rg];
            }
        }
        __syncthreads();

        {
            int p_loc = tid & 63, c0 = tid >> 6;
            int pg = n0 + p_loc;
            if (pg < 540){
                float m = dn ? 0.f : 1.f;
                #pragma unroll
                for (int e=0;e<8;++e){
                    int c_loc = c0*8 + e;
                    int cg = mh*64 + c_loc;
                    float gi = gsm[        c_loc*64 + p_loc] + lb[      cg];
                    float gf = gsm[ 4096 + c_loc*64 + p_loc] + lb[128 + cg];
                    float go = gsm[ 8192 + c_loc*64 + p_loc] + lb[256 + cg];
                    float gg = gsm[12288 + c_loc*64 + p_loc] + lb[384 + cg];
                    size_t idx = ((size_t)b*128 + cg)*540 + pg;
                    float cold = vc[idx] * m;
                    float cn = sigm(gf)*cold + sigm(gi)*tanhf(gg);
                    float hn = sigm(go)*tanhf(cn);
                    vc[idx] = cn;
                    if (t == T_-1) vh[idx] = hn;
                    unsigned short hb16 = f2bf(hn);
                    hwr[((size_t)b*540 + pg)*128 + cg] = hb16;
                    int flat = cg*540 + pg;
                    int pos = (flat/2560)*20 + (flat/128)%20;
                    int ch  = flat & 127;
                    hreA[((size_t)(t*B_ + b)*540 + pos)*128 + ch] = hb16;
                }
            }
        }
        return;
    }

    // ---------------- core recurrence step tc = t-1 ----------------
    if (t == 0) return;
    int tc = t - 1;
    int b = bid;
    float* fs = (float*)smraw;
    float* hs   = fs;          // 256
    float* cs   = fs + 256;    // 256
    float* hs2  = fs + 512;    // 256
    float* q1   = fs + 768;    // 128
    float* q2   = fs + 896;    // 288
    float* q3   = fs + 1184;   // 288
    float* elog = fs + 1472;   // 4*540
    float* red  = fs + 3632;   // 32
    float* ansv = fs + 3664;   // 1056
    float* hid  = fs + 4720;   // 512
    float* cis  = fs + 5232;   // 256
    float* gb   = fs + 5488;   // 1024

    if (tid < 256){ hs[tid] = hsb[b*256+tid]; cs[tid] = csb[b*256+tid]; }
    if (tid >= 256 && tid < 269) ansv[1043 + (tid-256)] = 0.f;   // pad rows of aw1 -> 0
    __syncthreads();

    float m = done[tc*B_+b] ? 0.f : 1.f;
    // ---- q1 = relu(hs @ qw1 + qb1)
    if (tid < 128){
        float a0=0.f,a1=0.f,a2=0.f,a3=0.f;
        for (int i8=0;i8<32;++i8){
            uint4 w = *((const uint4*)(pq1 + ((size_t)(i8<<7)+tid)*8));
            float4 ha = *((const float4*)(hs + i8*8));
            float4 hb2 = *((const float4*)(hs + i8*8 + 4));
            a0 += ha.x*BFLO(w.x);  a1 += ha.y*BFHI(w.x);
            a2 += ha.z*BFLO(w.y);  a3 += ha.w*BFHI(w.y);
            a0 += hb2.x*BFLO(w.z); a1 += hb2.y*BFHI(w.z);
            a2 += hb2.z*BFLO(w.w); a3 += hb2.w*BFHI(w.w);
        }
        q1[tid] = fmaxf(qb1[tid] + ((a0+a1)+(a2+a3)), 0.f);
    }
    __syncthreads();
    // ---- q2 = relu(q1 @ qw2 + qb2)
    if (tid < 288){
        float a0=0.f,a1=0.f,a2=0.f,a3=0.f;
        for (int i8=0;i8<16;++i8){
            uint4 w = *((const uint4*)(pq2 + ((size_t)i8*288+tid)*8));
            float4 ha = *((const float4*)(q1 + i8*8));
            float4 hb2 = *((const float4*)(q1 + i8*8 + 4));
            a0 += ha.x*BFLO(w.x);  a1 += ha.y*BFHI(w.x);
            a2 += ha.z*BFLO(w.y);  a3 += ha.w*BFHI(w.y);
            a0 += hb2.x*BFLO(w.z); a1 += hb2.y*BFHI(w.z);
            a2 += hb2.z*BFLO(w.w); a3 += hb2.w*BFHI(w.w);
        }
        q2[tid] = fmaxf(qb2[tid] + ((a0+a1)+(a2+a3)), 0.f);
    }
    __syncthreads();
    // ---- q3 = q2 @ qw3 + qb3
    if (tid < 288){
        float a0=0.f,a1=0.f,a2=0.f,a3=0.f;
        for (int i8=0;i8<36;++i8){
            uint4 w = *((const uint4*)(pq3 + ((size_t)i8*288+tid)*8));
            float4 ha = *((const float4*)(q2 + i8*8));
            float4 hb2 = *((const float4*)(q2 + i8*8 + 4));
            a0 += ha.x*BFLO(w.x);  a1 += ha.y*BFHI(w.x);
            a2 += ha.z*BFLO(w.y);  a3 += ha.w*BFHI(w.y);
            a0 += hb2.x*BFLO(w.z); a1 += hb2.y*BFHI(w.z);
            a2 += hb2.z*BFLO(w.w); a3 += hb2.w*BFHI(w.w);
        }
        float a = qb3[tid] + ((a0+a1)+(a2+a3));
        q3[tid] = a;
        ansv[736+tid] = a;
    }
    if (tid == 0){ float r = reward[tc*B_+b]; ansv[1024] = fminf(1.f,fmaxf(-1.f,r)); }
    if (tid >= 32 && tid < 32+NA) ansv[1025 + tid-32] = (lact[tc*B_+b] == tid-32) ? 1.f : 0.f;
    __syncthreads();

    // ---- attention logits
    const unsigned short* hrb = hreA + (size_t)(tc*B_ + b)*540*128;
    for (int idx = tid; idx < 4*P_; idx += 512){
        int qi = idx / P_, p = idx % P_;
        const unsigned short* hp = hrb + (size_t)p*128;
        uint4 hv = *((const uint4*)hp);
        const float* qv = q3 + qi*72;
        float a = BFLO(hv.x)*qv[0] + BFHI(hv.x)*qv[1]
                + BFLO(hv.y)*qv[2] + BFHI(hv.y)*qv[3]
                + BFLO(hv.z)*qv[4] + BFHI(hv.z)*qv[5]
                + BFLO(hv.w)*qv[6] + BFHI(hv.w)*qv[7];
        const float* Sp = S + p*64;
        #pragma unroll
        for (int s2=0;s2<16;++s2){
            float4 sv = *((const float4*)(Sp + 4*s2));
            a += sv.x*qv[8+4*s2] + sv.y*qv[9+4*s2] + sv.z*qv[10+4*s2] + sv.w*qv[11+4*s2];
        }
        elog[qi*P_ + p] = a;
    }
    __syncthreads();
    // ---- softmax (max, exp, sum) per query
    {
        int qi = tid >> 7, lt = tid & 127;
        float mx = -1e30f;
        for (int p = lt; p < P_; p += 128) mx = fmaxf(mx, elog[qi*P_ + p]);
        for (int off=32; off; off>>=1) mx = fmaxf(mx, __shfl_down(mx, off));
        if ((tid & 63) == 0) red[tid>>6] = mx;
        __syncthreads();
        if (tid < 4) red[16+tid] = fmaxf(red[2*tid], red[2*tid+1]);
        __syncthreads();
        mx = red[16+qi];
        float sm = 0.f;
        for (int p = lt; p < P_; p += 128){ float e = expf(elog[qi*P_ + p]-mx); elog[qi*P_ + p] = e; sm += e; }
        for (int off=32; off; off>>=1) sm += __shfl_down(sm, off);
        if ((tid & 63) == 0) red[8 + (tid>>6)] = sm;
        __syncthreads();
        if (tid < 4) red[24+tid] = red[8+2*tid] + red[8+2*tid+1];
        __syncthreads();
    }
    // ---- ans = softmax(A) @ V : V-part 8-lane p-split, then S-part via ST
    if (tid < 480){
        int g = tid >> 3;            // 60 groups: qi x vb(15 x 8ch)
        int qi = g / 15, vb = g % 15;
        int pc = tid & 7;
        float ac[8] = {0,0,0,0,0,0,0,0};
        const unsigned short* hb8 = hrb + 8 + vb*8;
        for (int p = pc; p < P_; p += 8){
            float e = elog[qi*P_ + p];
            uint4 hv = *((const uint4*)(hb8 + (size_t)p*128));
            ac[0] += e*BFLO(hv.x); ac[1] += e*BFHI(hv.x);
            ac[2] += e*BFLO(hv.y); ac[3] += e*BFHI(hv.y);
            ac[4] += e*BFLO(hv.z); ac[5] += e*BFHI(hv.z);
            ac[6] += e*BFLO(hv.w); ac[7] += e*BFHI(hv.w);
        }
        #pragma unroll
        for (int j=0;j<8;++j){ ac[j] += __shfl_down(ac[j],4); ac[j] += __shfl_down(ac[j],2); ac[j] += __shfl_down(ac[j],1); }
        if (pc == 0){
            float inv2 = 1.f/red[24+qi];
            #pragma unroll
            for (int j=0;j<8;++j) ansv[qi*184 + vb*8 + j] = ac[j]*inv2;
        }
    }
    {
        int g = tid >> 3;            // 64 groups: qi x vb4(16 x 4 rows of ST)
        int qi = g >> 4, vb4 = g & 15;
        int pc = tid & 7;
        float s0=0.f, s1=0.f, s2v=0.f, s3=0.f;
        const float* S0 = ST + (size_t)(vb4*4)*540;
        for (int p = pc; p < P_; p += 8){
            float e = elog[qi*P_ + p];
            s0 += e*S0[p]; s1 += e*S0[540+p]; s2v += e*S0[1080+p]; s3 += e*S0[1620+p];
        }
        s0 += __shfl_down(s0,4); s0 += __shfl_down(s0,2); s0 += __shfl_down(s0,1);
        s1 += __shfl_down(s1,4); s1 += __shfl_down(s1,2); s1 += __shfl_down(s1,1);
        s2v += __shfl_down(s2v,4); s2v += __shfl_down(s2v,2); s2v += __shfl_down(s2v,1);
        s3 += __shfl_down(s3,4); s3 += __shfl_down(s3,2); s3 += __shfl_down(s3,1);
        if (pc == 0){
            float inv2 = 1.f/red[24+qi];
            ansv[qi*184 + 120 + vb4*4 + 0] = s0*inv2;
            ansv[qi*184 + 120 + vb4*4 + 1] = s1*inv2;
            ansv[qi*184 + 120 + vb4*4 + 2] = s2v*inv2;
            ansv[qi*184 + 120 + vb4*4 + 3] = s3*inv2;
        }
    }
    __syncthreads();
    // ---- hid = relu(ansv @ aw1 + ab1)
    {
        float a0=ab1[tid], a1=0.f, a2=0.f, a3=0.f;
        for (int i8=0;i8<131;++i8){
            uint4 w = *((const uint4*)(pa1 + ((size_t)(i8<<9)+tid)*8));
            float4 av = *((const float4*)(ansv + i8*8));
            float4 av2 = *((const float4*)(ansv + i8*8 + 4));
            a0 += av.x*BFLO(w.x);  a1 += av.y*BFHI(w.x);
            a2 += av.z*BFLO(w.y);  a3 += av.w*BFHI(w.y);
            a0 += av2.x*BFLO(w.z); a1 += av2.y*BFHI(w.z);
            a2 += av2.z*BFLO(w.w); a3 += av2.w*BFHI(w.w);
        }
        hid[tid] = fmaxf((a0+a1)+(a2+a3), 0.f);
    }
    if (tid < 256) hs2[tid] = hs[tid]*m;
    __syncthreads();
    // ---- cis = hid @ aw2 + ab2
    if (tid < 256){
        float a0=ab2[tid],a1=0.f,a2=0.f,a3=0.f;
        for (int i8=0;i8<64;++i8){
            uint4 w = *((const uint4*)(pa2 + ((size_t)(i8<<8)+tid)*8));
            float4 hv = *((const float4*)(hid + i8*8));
            float4 hv2 = *((const float4*)(hid + i8*8 + 4));
            a0 += hv.x*BFLO(w.x);  a1 += hv.y*BFHI(w.x);
            a2 += hv.z*BFLO(w.y);  a3 += hv.w*BFHI(w.y);
            a0 += hv2.x*BFLO(w.z); a1 += hv2.y*BFHI(w.z);
            a2 += hv2.z*BFLO(w.w); a3 += hv2.w*BFHI(w.w);
        }
        cis[tid] = (a0+a1)+(a2+a3);
    }
    __syncthreads();
    // ---- gates = cis @ w_ih^T + hs2 @ w_hh^T + b
    for (int g = tid; g < 1024; g += 512){
        float a0=bih[g]+bhh[g], a1=0.f, a2=0.f, a3=0.f;
        for (int i8=0;i8<32;++i8){
            uint4 wi = *((const uint4*)(pih + ((size_t)(i8<<10)+g)*8));
            uint4 wh = *((const uint4*)(phh + ((size_t)(i8<<10)+g)*8));
            float4 ca = *((const float4*)(cis + i8*8));
            float4 cb2 = *((const float4*)(cis + i8*8 + 4));
            float4 ha = *((const float4*)(hs2 + i8*8));
            float4 hb2 = *((const float4*)(hs2 + i8*8 + 4));
            a0 += ca.x*BFLO(wi.x) + ha.x*BFLO(wh.x);
            a1 += ca.y*BFHI(wi.x) + ha.y*BFHI(wh.x);
            a2 += ca.z*BFLO(wi.y) + ha.z*BFLO(wh.y);
            a3 += ca.w*BFHI(wi.y) + ha.w*BFHI(wh.y);
            a0 += cb2.x*BFLO(wi.z) + hb2.x*BFLO(wh.z);
            a1 += cb2.y*BFHI(wi.z) + hb2.y*BFHI(wh.z);
            a2 += cb2.z*BFLO(wi.w) + hb2.z*BFLO(wh.w);
            a3 += cb2.w*BFHI(wi.w) + hb2.w*BFHI(wh.w);
        }
        gb[g] = (a0+a1)+(a2+a3);
    }
    __syncthreads();
    if (tid < 256){
        float gi = gb[tid], gf = gb[256+tid], gg = gb[512+tid], go = gb[768+tid];
        float cold = cs[tid]*m;
        float cn = sigm(gf)*cold + sigm(gi)*tanhf(gg);
        float hn = sigm(go)*tanhf(cn);
        csb[b*256+tid] = cn;
        hsb[b*256+tid] = hn;
        outs[(tc*B_+b)*256+tid] = hn;
    }
}

// ---------------- heads
__global__ __launch_bounds__(64) void finalk(const float* __restrict__ outs,
                                             const float* __restrict__ pw, const float* __restrict__ pb,
                                             const float* __restrict__ vw, const float* __restrict__ vb,
                                             float* __restrict__ dout){
    int row = blockIdx.x, tid = threadIdx.x;
    __shared__ float os[256];
    __shared__ float lg[NA];
    for (int i=tid; i<256; i+=64) os[i] = outs[row*256+i];
    __syncthreads();
    if (tid < NA){
        float a = pb[tid];
        for (int i=0;i<256;++i) a += os[i]*pw[i*NA+tid];
        lg[tid] = a;
        dout[row*NA + tid] = a;
    } else if (tid == 32){
        float a = vb[0];
        for (int i=0;i<256;++i) a += os[i]*vw[i];
        dout[9216 + row] = a;
    }
    __syncthreads();
    if (tid == 0){
        int am = 0; float bv = lg[0];
        for (int j=1;j<NA;++j) if (lg[j] > bv){ bv = lg[j]; am = j; }
        dout[9728 + row] = (float)am;
    }
}

extern "C" void kernel_launch(void* const* d_in, const int* in_sizes, int n_in,
                              void* d_out, int out_size, void* d_ws, size_t ws_size,
                              hipStream_t stream) {
    const float* frame   = (const float*)d_in[0];
    const unsigned char* done = (const unsigned char*)d_in[1];
    const int*   lact    = (const int*)d_in[2];
    const float* reward  = (const float*)d_in[3];
    const float* core_h0 = (const float*)d_in[4];
    const float* core_c0 = (const float*)d_in[5];
    const float* conv_h0 = (const float*)d_in[6];
    const float* conv_c0 = (const float*)d_in[7];
    const float* cnn_w1  = (const float*)d_in[8];
    const float* cnn_b1  = (const float*)d_in[9];
    const float* cnn_w2  = (const float*)d_in[10];
    const float* cnn_b2  = (const float*)d_in[11];
    const float* lstm_w  = (const float*)d_in[12];
    const float* lstm_b  = (const float*)d_in[13];
    const float* qw1 = (const float*)d_in[14]; const float* qb1 = (const float*)d_in[15];
    const float* qw2 = (const float*)d_in[16]; const float* qb2 = (const float*)d_in[17];
    const float* qw3 = (const float*)d_in[18]; const float* qb3 = (const float*)d_in[19];
    const float* aw1 = (const float*)d_in[20]; const float* ab1 = (const float*)d_in[21];
    const float* aw2 = (const float*)d_in[22]; const float* ab2 = (const float*)d_in[23];
    const float* w_ih = (const float*)d_in[24]; const float* w_hh = (const float*)d_in[25];
    const float* b_ih = (const float*)d_in[26]; const float* b_hh = (const float*)d_in[27];
    const float* pw = (const float*)d_in[28]; const float* pb = (const float*)d_in[29];
    const float* vw = (const float*)d_in[30]; const float* vb = (const float*)d_in[31];

    float* ws = (float*)d_ws;
    float* dout = (float*)d_out;

    // ws layout (float offsets)
    unsigned short* xre    = (unsigned short*)ws;                         // 17,694,720 u16
    unsigned short* hreA   = (unsigned short*)(ws + 10485760);            // 35,389,440 u16
    unsigned short* apack  = (unsigned short*)(ws + 28180480);            // 884,736 u16
    unsigned short* wpk    = (unsigned short*)(ws + 28966912);            // packed core weights (x8)
    unsigned short* pq1 = wpk;            // 32,768
    unsigned short* pq2 = wpk + 32768;    // 36,864
    unsigned short* pq3 = wpk + 69632;    // 82,944
    unsigned short* pa1 = wpk + 152576;   // 536,576
    unsigned short* pa2 = wpk + 689152;   // 131,072
    unsigned short* pih = wpk + 820224;   // 262,144
    unsigned short* phh = wpk + 1082368;  // 262,144 (ends 1,344,512 u16 = 672,256 fl)
    unsigned short* h0re   = (unsigned short*)(ws + 29753344);            // 1,105,920 u16
    unsigned short* apack2 = (unsigned short*)(ws + 30408704);            // 32,768 u16
    unsigned short* hpl0   = (unsigned short*)(ws + 30425088);            // 1,105,920 u16
    float* hsb   = ws + 31080448;      // 4,096
    float* csb   = ws + 31084544;      // 4,096
    unsigned short* hpl1   = (unsigned short*)(ws + 31100928);            // 1,105,920 u16 (ends 31,653,888)
    unsigned short* c1buf  = (unsigned short*)(ws + 31653888);            // 3,612,672 u16 (3 slots, ends 33,460,224)
    float* ST    = ws + 33460224;      // 34,560 (ends 33,494,784)
    float* vh    = ws + 34881536;      // 1,105,920
    float* vc    = ws + 35987456;      // 1,105,920
    float* S     = ws + 37093376;      // 34,560
    float* outs  = ws + 37127936;      // 131,072 (ends 37,259,008)

    // zero c1buf halo once (interiors overwritten each reuse)
    hipMemsetAsync(c1buf, 0, (size_t)3612672*2, stream);

    apack2k<<<128, 256, 0, stream>>>(cnn_w2, apack2);
    sbasisk<<<135, 256, 0, stream>>>(S, ST);
    apack9k<<<3456, 256, 0, stream>>>(lstm_w, apack);
    packw8k<<<128,  256, 0, stream>>>(qw1, pq1, 256, 128);
    packw8k<<<144,  256, 0, stream>>>(qw2, pq2, 128, 288);
    packw8k<<<324,  256, 0, stream>>>(qw3, pq3, 288, 288);
    packw8k<<<2096, 256, 0, stream>>>(aw1, pa1, 1043, 512);
    packw8k<<<512,  256, 0, stream>>>(aw2, pa2, 512, 256);
    packt8k<<<1024, 256, 0, stream>>>(w_ih, pih, 256, 1024);
    packt8k<<<1024, 256, 0, stream>>>(w_hh, phh, 256, 1024);
    h0rek<<<4320, 256, 0, stream>>>(conv_h0, h0re);
    hipMemcpyAsync(vc,  conv_c0, (size_t)16*128*540*sizeof(float), hipMemcpyDeviceToDevice, stream);
    hipMemcpyAsync(hsb, core_h0, (size_t)16*256*sizeof(float), hipMemcpyDeviceToDevice, stream);
    hipMemcpyAsync(csb, core_c0, (size_t)16*256*sizeof(float), hipMemcpyDeviceToDevice, stream);

    // prologue CNN: frames t'=0,1 through conv1; frame t'=0 through conv2
    conv1pro<<<832, 512, 0, stream>>>(frame, cnn_w1, cnn_b1, c1buf);
    c2pro<<<80, 512, 0, stream>>>(c1buf, apack2, cnn_b2, xre);

    // pipelined loop: core(t-1) || vis(t) || conv1(t+2) || conv2(t+1)  (33 dispatches)
    for (int t = 0; t <= T_; ++t){
        gvck<<<800, 512, 0, stream>>>(frame, cnn_w1, cnn_b1, c1buf, apack2, cnn_b2, xre,
                                      (t&1)?hpl0:hpl1, (t&1)?hpl1:hpl0, h0re,
                                      apack, lstm_b, done, vh, vc, hreA,
                                      S, ST, pq1,qb1,pq2,qb2,pq3,qb3,
                                      pa1,ab1,pa2,ab2, pih,phh,b_ih,b_hh,
                                      reward, lact, hsb, csb, outs, t);
    }

    finalk<<<512, 64, 0, stream>>>(outs, pw, pb, vw, vb, dout);

    hipMemcpyAsync(dout + 10240,   outs + (size_t)31*B_*256, (size_t)16*256*sizeof(float), hipMemcpyDeviceToDevice, stream);
    hipMemcpyAsync(dout + 14336,   csb, (size_t)16*256*sizeof(float), hipMemcpyDeviceToDevice, stream);
    hipMemcpyAsync(dout + 18432,   vh,  (size_t)16*128*540*sizeof(float), hipMemcpyDeviceToDevice, stream);
    hipMemcpyAsync(dout + 1124352, vc,  (size_t)16*128*540*sizeof(float), hipMemcpyDeviceToDevice, stream);
}

// Round 9
// 4723.292 us; speedup vs baseline: 1.1325x; 1.1325x over previous
//
#include <hip/hip_runtime.h>
#include <math.h>

#define T_ 32
#define B_ 16
#define NA 18
#define P_ 540   /* 27*20 spatial positions */

typedef __attribute__((ext_vector_type(8)))  short short8;
typedef __attribute__((ext_vector_type(16))) float f32x16;

__device__ __forceinline__ float sigm(float x){ return 1.0f/(1.0f+expf(-x)); }
__device__ __forceinline__ unsigned short f2bf(float f){
    unsigned u = __float_as_uint(f);
    u += 0x7fff + ((u>>16)&1u);
    return (unsigned short)(u>>16);
}
__device__ __forceinline__ float bfu(unsigned short u){ return __uint_as_float(((unsigned)u)<<16); }
__device__ __forceinline__ float BFLO(unsigned x){ return __uint_as_float(x<<16); }
__device__ __forceinline__ float BFHI(unsigned x){ return __uint_as_float(x & 0xffff0000u); }

// conv1: (512,3,210,160) -> c1pad bf16 [512][32][56][42], k8 s4 padH(1,1) W(2,2).
// Two output rows per block (12-row input tile): 80 FMA per weight-load pair.
__global__ __launch_bounds__(256) void conv1k(const float* __restrict__ frame,
                                              const float* __restrict__ w,
                                              const float* __restrict__ bias,
                                              unsigned short* __restrict__ c1pad){
    __shared__ float tile[6048];  // 3 ch x 12 rows x 168 cols
    int bid = blockIdx.x;
    int n = bid / 26, oh = (bid % 26)*2;
    int tid = threadIdx.x;
    const float* fb = frame + (size_t)n*3*210*160;
    for (int s = tid; s < 6048; s += 256){
        int col = s % 168;
        int row = (s/168) % 12;
        int ic  = s / 2016;
        int iy = oh*4 - 1 + row;
        int ix = col - 2;
        float v = 0.f;
        if (iy >= 0 && iy < 210 && ix >= 0 && ix < 160) v = fb[ic*33600 + iy*160 + ix];
        tile[s] = v;
    }
    __syncthreads();
    int oc = tid & 31, grp = tid >> 5;
    float acc[10] = {0.f,0.f,0.f,0.f,0.f,0.f,0.f,0.f,0.f,0.f};
    const float* wb = w + oc*192;
    for (int ic=0; ic<3; ++ic){
        #pragma unroll
        for (int kh=0; kh<8; ++kh){
            const float* wr = wb + ic*64 + kh*8;
            float4 w0 = *((const float4*)wr);
            float4 w1 = *((const float4*)(wr+4));
            const float* rowA = tile + ic*2016 + kh*168 + grp*20;
            float r[24];
            *((float4*)(r+ 0)) = *((const float4*)(rowA+ 0));
            *((float4*)(r+ 4)) = *((const float4*)(rowA+ 4));
            *((float4*)(r+ 8)) = *((const float4*)(rowA+ 8));
            *((float4*)(r+12)) = *((const float4*)(rowA+12));
            *((float4*)(r+16)) = *((const float4*)(rowA+16));
            *((float4*)(r+20)) = *((const float4*)(rowA+20));
            #pragma unroll
            for (int o=0;o<5;++o){
                acc[o] += r[o*4+0]*w0.x + r[o*4+1]*w0.y + r[o*4+2]*w0.z + r[o*4+3]*w0.w
                        + r[o*4+4]*w1.x + r[o*4+5]*w1.y + r[o*4+6]*w1.z + r[o*4+7]*w1.w;
            }
            const float* rowB = rowA + 672;
            *((float4*)(r+ 0)) = *((const float4*)(rowB+ 0));
            *((float4*)(r+ 4)) = *((const float4*)(rowB+ 4));
            *((float4*)(r+ 8)) = *((const float4*)(rowB+ 8));
            *((float4*)(r+12)) = *((const float4*)(rowB+12));
            *((float4*)(r+16)) = *((const float4*)(rowB+16));
            *((float4*)(r+20)) = *((const float4*)(rowB+20));
            #pragma unroll
            for (int o=0;o<5;++o){
                acc[5+o] += r[o*4+0]*w0.x + r[o*4+1]*w0.y + r[o*4+2]*w0.z + r[o*4+3]*w0.w
                          + r[o*4+4]*w1.x + r[o*4+5]*w1.y + r[o*4+6]*w1.z + r[o*4+7]*w1.w;
            }
        }
    }
    float bi = bias[oc];
    unsigned short* ob = c1pad + ((size_t)(n*32 + oc)*56 + oh+2)*42 + 1;
    #pragma unroll
    for (int o=0;o<5;++o) ob[grp*5+o] = f2bf(acc[o] + bi);
    ob += 42;
    #pragma unroll
    for (int o=0;o<5;++o) ob[grp*5+o] = f2bf(acc[5+o] + bi);
}

// conv2 A-operand pack: cnn_w2 (64,32,4,4) -> apack2[32 ic][2 mt][64 lane][8] bf16
__global__ void apack2k(const float* __restrict__ w2, unsigned short* __restrict__ ap){
    int idx = blockIdx.x*256 + threadIdx.x;
    if (idx >= 32768) return;
    int j = idx & 7;
    int lane = (idx>>3) & 63;
    int mt = (idx>>9) & 1;
    int ic = idx >> 10;
    int k = ((lane>>5)<<3) + j;
    int oc = mt*32 + (lane & 31);
    ap[idx] = f2bf(w2[((oc*32 + ic)<<4) + k]);
}

// conv2 MFMA: c1pad bf16 -> xre bf16 [512][540 pos][64 oc]
__global__ __launch_bounds__(256) void c2mfma(const unsigned short* __restrict__ c1pad,
                                              const unsigned short* __restrict__ apack2,
                                              const float* __restrict__ bias,
                                              unsigned short* __restrict__ xre){
    __shared__ unsigned short p2[2][3072];
    __shared__ float bsm[64];
    int bid = blockIdx.x;
    int s = bid / 5;
    int n0 = (bid % 5) * 128;
    int tid = threadIdx.x;
    int wave = tid >> 6, lane = tid & 63;
    int khalf = (lane>>5) << 3;
    if (tid < 64) bsm[tid] = bias[tid];
    const unsigned short* cb = c1pad + (size_t)s*32*2352;

    int soff[8], swaddr[8];
    #pragma unroll
    for (int q=0;q<8;++q){
        int idx = q*256 + tid;
        int n = idx & 127, k = idx >> 7;
        int p = n0 + n; if (p > 539) p = 539;
        soff[q] = ((p/20)*2 + (k>>2))*42 + (p%20)*2 + (k&3);
        swaddr[q] = n*24 + k;
    }
    #pragma unroll
    for (int q=0;q<8;++q) p2[0][swaddr[q]] = cb[soff[q]];
    unsigned short rv[8];
    #pragma unroll
    for (int q=0;q<8;++q) rv[q] = cb[2352 + soff[q]];

    int mt = wave >> 1, ntb = (wave & 1) * 2;
    short8 acur = *((const short8*)(apack2 + ((size_t)mt*64 + lane)*8));
    short8 anxt;
    f32x16 acc[2];
    #pragma unroll
    for (int jj=0;jj<2;++jj)
        #pragma unroll
        for (int rg=0;rg<16;++rg) acc[jj][rg] = 0.f;
    __syncthreads();

    for (int c=0; c<32; ++c){
        int buf = c & 1;
        if (c < 31){
            #pragma unroll
            for (int q=0;q<8;++q) p2[buf^1][swaddr[q]] = rv[q];
        }
        if (c < 30){
            const unsigned short* src = cb + (size_t)(c+2)*2352;
            #pragma unroll
            for (int q=0;q<8;++q) rv[q] = src[soff[q]];
        }
        if (c < 31) anxt = *((const short8*)(apack2 + ((size_t)((c+1)*2 + mt)*64 + lane)*8));
        #pragma unroll
        for (int jj=0;jj<2;++jj){
            int n = (ntb+jj)*32 + (lane & 31);
            short8 bf = *((const short8*)(&p2[buf][n*24 + khalf]));
            acc[jj] = __builtin_amdgcn_mfma_f32_32x32x16_bf16(acur, bf, acc[jj], 0, 0, 0);
        }
        acur = anxt;
        __syncthreads();
    }
    #pragma unroll
    for (int jj=0;jj<2;++jj){
        int pos = n0 + (ntb+jj)*32 + (lane & 31);
        if (pos >= 540) continue;
        unsigned short* op = xre + ((size_t)s*540 + pos)*64;
        #pragma unroll
        for (int rg=0; rg<16; ++rg){
            int oc = mt*32 + (rg & 3) + 8*(rg>>2) + 4*(lane>>5);
            op[oc] = f2bf(acc[jj][rg] + bsm[oc]);
        }
    }
}

// spatial basis S[540][64] and its transpose ST[64][540]
__global__ void sbasisk(float* __restrict__ S, float* __restrict__ ST){
    int idx = blockIdx.x*256 + threadIdx.x;
    if (idx >= P_*64) return;
    int s = idx & 63, p = idx >> 6;
    int y = p/20, x = p%20;
    int u = s >> 3, v = s & 7;
    double a  = cos((double)((y+1)*(u+1)) * M_PI / 27.0);
    double bb = cos((double)((x+1)*(v+1)) * M_PI / 20.0);
    float fv = (float)(a*bb);
    S[idx] = fv;
    ST[(size_t)s*540 + p] = fv;
}

// weight pack x8: f32 [R][C] -> bf16 [(R+7)/8][C][8], pad rows zero
__global__ void packw8k(const float* __restrict__ in, unsigned short* __restrict__ out, int R, int C){
    int idx = blockIdx.x*256 + threadIdx.x;
    int r8cnt = (R+7)>>3;
    if (idx >= r8cnt*C*8) return;
    int j = idx & 7;
    int rc = idx >> 3;
    int c = rc % C;
    int r = (rc / C)*8 + j;
    out[idx] = (r < R) ? f2bf(in[(size_t)r*C + c]) : (unsigned short)0;
}
// weight pack x8 from transposed source: f32 [C][R] -> bf16 [(R+7)/8][C][8]
__global__ void packt8k(const float* __restrict__ in, unsigned short* __restrict__ out, int R, int C){
    int idx = blockIdx.x*256 + threadIdx.x;
    int r8cnt = (R+7)>>3;
    if (idx >= r8cnt*C*8) return;
    int j = idx & 7;
    int rc = idx >> 3;
    int c = rc % C;
    int r = (rc / C)*8 + j;
    out[idx] = (r < R) ? f2bf(in[(size_t)c*R + r]) : (unsigned short)0;
}

// ConvLSTM gates A-pack (tap-wise): lstm_w (512,192,3,3) ->
// ap[tap 9][chunk 12][16 mt][64 lane][8] bf16; K = 192 channels, no zero-padding waste
__global__ void apack9k(const float* __restrict__ lw, unsigned short* __restrict__ ap){
    int idx = blockIdx.x*256 + threadIdx.x;
    if (idx >= 884736) return;
    int j = idx & 7;
    int lane = (idx>>3) & 63;
    int mt = (idx>>9) & 15;
    int f  = idx >> 13;
    int tap = f / 12, c = f % 12;
    int ch = c*16 + ((lane>>5)<<3) + j;
    int oc = mt*32 + (lane & 31);
    ap[idx] = f2bf(lw[(size_t)oc*1728 + ch*9 + tap]);
}

// conv_h0 fp32 [b][128][540] -> h0re bf16 [b][540 pos][128 ch] (true spatial layout)
__global__ void h0rek(const float* __restrict__ h0, unsigned short* __restrict__ h0re){
    int idx = blockIdx.x*256 + threadIdx.x;
    if (idx >= 16*128*540) return;
    int plane = idx / 540, p = idx % 540;
    int b = plane >> 7, c = plane & 127;
    h0re[((size_t)b*540 + p)*128 + c] = f2bf(h0[idx]);
}

// =====================================================================================
// gvpk: ONE dispatch per t runs both pipeline stages concurrently:
//   blocks 0..15   : core recurrence step t-1 (critical chain, scheduled first;
//                    x8-packed bf16 weights stay L2-resident)
//   blocks 16..303 : vis ConvLSTM step t (direct-global MFMA conv + fused pointwise)
// 304 blocks -> most CUs hold one block; cross-stage deps span a dispatch boundary.
// =====================================================================================
__global__ __launch_bounds__(512) void gvpk(const unsigned short* __restrict__ xre,
                                            const unsigned short* __restrict__ hrd,
                                            unsigned short* __restrict__ hwr,
                                            const unsigned short* __restrict__ h0re,
                                            const unsigned short* __restrict__ apack,
                                            const float* __restrict__ lb,
                                            const unsigned char* __restrict__ done,
                                            float* __restrict__ vh, float* __restrict__ vc,
                                            unsigned short* __restrict__ hreA,
                                            const float* __restrict__ S,
                                            const float* __restrict__ ST,
                                            const unsigned short* __restrict__ pq1, const float* __restrict__ qb1,
                                            const unsigned short* __restrict__ pq2, const float* __restrict__ qb2,
                                            const unsigned short* __restrict__ pq3, const float* __restrict__ qb3,
                                            const unsigned short* __restrict__ pa1, const float* __restrict__ ab1,
                                            const unsigned short* __restrict__ pa2, const float* __restrict__ ab2,
                                            const unsigned short* __restrict__ pih, const unsigned short* __restrict__ phh,
                                            const float* __restrict__ bih, const float* __restrict__ bhh,
                                            const float* __restrict__ reward, const int* __restrict__ lact,
                                            float* __restrict__ hsb, float* __restrict__ csb,
                                            float* __restrict__ outs,
                                            int t){
    __shared__ __align__(16) char smraw[65536];
    int bid = blockIdx.x;
    int tid = threadIdx.x;

    if (bid >= 16){
        // ======== vis ConvLSTM step t ========
        if (t >= T_) return;
        float* gsm = (float*)smraw;                    // [4 gates][64 ch][64 pos] f32
        int vb = bid - 16;
        int b  = vb % 16;
        int r  = vb / 16;
        int nb = r % 9;
        int mh = r / 9;
        int wave = tid >> 6, lane = tid & 63;
        int khalf = (lane>>5) << 3;
        int n0 = nb * 64;
        bool dn = done[t*B_ + b];

        const unsigned short* xb = xre + (size_t)(t*B_ + b)*540*64;
        const unsigned short* hp2 = (t==0) ? (h0re + (size_t)b*540*128)
                                           : (hrd  + (size_t)b*540*128);

        int mt = (wave>>1)*4 + mh*2 + (wave&1);

        int poff[2][9]; int vmask[2][9];
        #pragma unroll
        for (int jj=0;jj<2;++jj){
            int p = n0 + jj*32 + (lane & 31); if (p > 539) p = 539;
            int y = p/20, x = p%20;
            #pragma unroll
            for (int tap=0;tap<9;++tap){
                int dy = tap/3 - 1, dx = tap%3 - 1;
                int yy = y+dy, xx = x+dx;
                vmask[jj][tap] = ((unsigned)yy < 27u) && ((unsigned)xx < 20u);
                poff[jj][tap] = yy*20 + xx;
            }
        }
        const short8 z8 = {0,0,0,0,0,0,0,0};
        f32x16 acc[2];
        #pragma unroll
        for (int jj=0;jj<2;++jj)
            #pragma unroll
            for (int rg=0;rg<16;++rg) acc[jj][rg] = 0.f;

        for (int c=0;c<4;++c){
            int cho = c*16 + khalf;
            #pragma unroll
            for (int tap=0;tap<9;++tap){
                short8 af = *((const short8*)(apack + ((size_t)((tap*12+c)*16 + mt)*64 + lane)*8));
                short8 b0 = vmask[0][tap] ? *((const short8*)(xb + poff[0][tap]*64 + cho)) : z8;
                short8 b1 = vmask[1][tap] ? *((const short8*)(xb + poff[1][tap]*64 + cho)) : z8;
                acc[0] = __builtin_amdgcn_mfma_f32_32x32x16_bf16(af, b0, acc[0], 0, 0, 0);
                acc[1] = __builtin_amdgcn_mfma_f32_32x32x16_bf16(af, b1, acc[1], 0, 0, 0);
            }
        }
        if (!dn){
            for (int c=4;c<12;++c){
                int cho = (c-4)*16 + khalf;
                #pragma unroll
                for (int tap=0;tap<9;++tap){
                    short8 af = *((const short8*)(apack + ((size_t)((tap*12+c)*16 + mt)*64 + lane)*8));
                    short8 b0 = vmask[0][tap] ? *((const short8*)(hp2 + poff[0][tap]*128 + cho)) : z8;
                    short8 b1 = vmask[1][tap] ? *((const short8*)(hp2 + poff[1][tap]*128 + cho)) : z8;
                    acc[0] = __builtin_amdgcn_mfma_f32_32x32x16_bf16(af, b0, acc[0], 0, 0, 0);
                    acc[1] = __builtin_amdgcn_mfma_f32_32x32x16_bf16(af, b1, acc[1], 0, 0, 0);
                }
            }
        }

        int g8 = wave >> 1, ih = wave & 1;
        #pragma unroll
        for (int j=0;j<2;++j){
            int p_loc = j*32 + (lane & 31);
            #pragma unroll
            for (int rg=0; rg<16; ++rg){
                int c_loc = ih*32 + 4*(lane>>5) + (rg & 3) + 8*(rg>>2);
                gsm[g8*4096 + c_loc*64 + p_loc] = acc[j][rg];
            }
        }
        __syncthreads();

        {
            int p_loc = tid & 63, c0 = tid >> 6;
            int pg = n0 + p_loc;
            if (pg < 540){
                float m = dn ? 0.f : 1.f;
                #pragma unroll
                for (int e=0;e<8;++e){
                    int c_loc = c0*8 + e;
                    int cg = mh*64 + c_loc;
                    float gi = gsm[        c_loc*64 + p_loc] + lb[      cg];
                    float gf = gsm[ 4096 + c_loc*64 + p_loc] + lb[128 + cg];
                    float go = gsm[ 8192 + c_loc*64 + p_loc] + lb[256 + cg];
                    float gg = gsm[12288 + c_loc*64 + p_loc] + lb[384 + cg];
                    size_t idx = ((size_t)b*128 + cg)*540 + pg;
                    float cold = vc[idx] * m;
                    float cn = sigm(gf)*cold + sigm(gi)*tanhf(gg);
                    float hn = sigm(go)*tanhf(cn);
                    vc[idx] = cn;
                    if (t == T_-1) vh[idx] = hn;
                    unsigned short hb16 = f2bf(hn);
                    hwr[((size_t)b*540 + pg)*128 + cg] = hb16;
                    int flat = cg*540 + pg;
                    int pos = (flat/2560)*20 + (flat/128)%20;
                    int ch  = flat & 127;
                    hreA[((size_t)(t*B_ + b)*540 + pos)*128 + ch] = hb16;
                }
            }
        }
        return;
    }

    // ======== core recurrence step tc = t-1 ========
    if (t == 0) return;
    int tc = t - 1;
    int b = bid;
    float* fs = (float*)smraw;
    float* hs   = fs;          // 256
    float* cs   = fs + 256;    // 256
    float* hs2  = fs + 512;    // 256
    float* q1   = fs + 768;    // 128
    float* q2   = fs + 896;    // 288
    float* q3   = fs + 1184;   // 288
    float* elog = fs + 1472;   // 4*540
    float* red  = fs + 3632;   // 32
    float* ansv = fs + 3664;   // 1056
    float* hid  = fs + 4720;   // 512
    float* cis  = fs + 5232;   // 256
    float* gb   = fs + 5488;   // 1024 (ends 6512 floats = 26 KB)

    if (tid < 256){ hs[tid] = hsb[b*256+tid]; cs[tid] = csb[b*256+tid]; }
    if (tid >= 256 && tid < 269) ansv[1043 + (tid-256)] = 0.f;   // zero aw1 K-pad rows
    __syncthreads();

    float m = done[tc*B_+b] ? 0.f : 1.f;
    // q1 = relu(hs @ qw1 + qb1), x8-packed
    if (tid < 128){
        float a0=0.f,a1=0.f,a2=0.f,a3=0.f;
        for (int i8=0;i8<32;++i8){
            uint4 w = *((const uint4*)(pq1 + ((size_t)(i8<<7)+tid)*8));
            float4 ha = *((const float4*)(hs + i8*8));
            float4 hb2 = *((const float4*)(hs + i8*8 + 4));
            a0 += ha.x*BFLO(w.x);  a1 += ha.y*BFHI(w.x);
            a2 += ha.z*BFLO(w.y);  a3 += ha.w*BFHI(w.y);
            a0 += hb2.x*BFLO(w.z); a1 += hb2.y*BFHI(w.z);
            a2 += hb2.z*BFLO(w.w); a3 += hb2.w*BFHI(w.w);
        }
        q1[tid] = fmaxf(qb1[tid] + ((a0+a1)+(a2+a3)), 0.f);
    }
    __syncthreads();
    // q2 = relu(q1 @ qw2 + qb2)
    if (tid < 288){
        float a0=0.f,a1=0.f,a2=0.f,a3=0.f;
        for (int i8=0;i8<16;++i8){
            uint4 w = *((const uint4*)(pq2 + ((size_t)i8*288+tid)*8));
            float4 ha = *((const float4*)(q1 + i8*8));
            float4 hb2 = *((const float4*)(q1 + i8*8 + 4));
            a0 += ha.x*BFLO(w.x);  a1 += ha.y*BFHI(w.x);
            a2 += ha.z*BFLO(w.y);  a3 += ha.w*BFHI(w.y);
            a0 += hb2.x*BFLO(w.z); a1 += hb2.y*BFHI(w.z);
            a2 += hb2.z*BFLO(w.w); a3 += hb2.w*BFHI(w.w);
        }
        q2[tid] = fmaxf(qb2[tid] + ((a0+a1)+(a2+a3)), 0.f);
    }
    __syncthreads();
    // q3 = q2 @ qw3 + qb3
    if (tid < 288){
        float a0=0.f,a1=0.f,a2=0.f,a3=0.f;
        for (int i8=0;i8<36;++i8){
            uint4 w = *((const uint4*)(pq3 + ((size_t)i8*288+tid)*8));
            float4 ha = *((const float4*)(q2 + i8*8));
            float4 hb2 = *((const float4*)(q2 + i8*8 + 4));
            a0 += ha.x*BFLO(w.x);  a1 += ha.y*BFHI(w.x);
            a2 += ha.z*BFLO(w.y);  a3 += ha.w*BFHI(w.y);
            a0 += hb2.x*BFLO(w.z); a1 += hb2.y*BFHI(w.z);
            a2 += hb2.z*BFLO(w.w); a3 += hb2.w*BFHI(w.w);
        }
        float a = qb3[tid] + ((a0+a1)+(a2+a3));
        q3[tid] = a;
        ansv[736+tid] = a;
    }
    if (tid == 0){ float r = reward[tc*B_+b]; ansv[1024] = fminf(1.f,fmaxf(-1.f,r)); }
    if (tid >= 32 && tid < 32+NA) ansv[1025 + tid-32] = (lact[tc*B_+b] == tid-32) ? 1.f : 0.f;
    __syncthreads();

    // attention logits
    const unsigned short* hrb = hreA + (size_t)(tc*B_ + b)*540*128;
    for (int idx = tid; idx < 4*P_; idx += 512){
        int qi = idx / P_, p = idx % P_;
        const unsigned short* hp = hrb + (size_t)p*128;
        uint4 hv = *((const uint4*)hp);
        const float* qv = q3 + qi*72;
        float a = BFLO(hv.x)*qv[0] + BFHI(hv.x)*qv[1]
                + BFLO(hv.y)*qv[2] + BFHI(hv.y)*qv[3]
                + BFLO(hv.z)*qv[4] + BFHI(hv.z)*qv[5]
                + BFLO(hv.w)*qv[6] + BFHI(hv.w)*qv[7];
        const float* Sp = S + p*64;
        #pragma unroll
        for (int s2=0;s2<16;++s2){
            float4 sv = *((const float4*)(Sp + 4*s2));
            a += sv.x*qv[8+4*s2] + sv.y*qv[9+4*s2] + sv.z*qv[10+4*s2] + sv.w*qv[11+4*s2];
        }
        elog[qi*P_ + p] = a;
    }
    __syncthreads();
    // softmax per query (max, exp, sum)
    {
        int qi = tid >> 7, lt = tid & 127;
        float mx = -1e30f;
        for (int p = lt; p < P_; p += 128) mx = fmaxf(mx, elog[qi*P_ + p]);
        for (int off=32; off; off>>=1) mx = fmaxf(mx, __shfl_down(mx, off));
        if ((tid & 63) == 0) red[tid>>6] = mx;
        __syncthreads();
        if (tid < 4) red[16+tid] = fmaxf(red[2*tid], red[2*tid+1]);
        __syncthreads();
        mx = red[16+qi];
        float sm = 0.f;
        for (int p = lt; p < P_; p += 128){ float e = expf(elog[qi*P_ + p]-mx); elog[qi*P_ + p] = e; sm += e; }
        for (int off=32; off; off>>=1) sm += __shfl_down(sm, off);
        if ((tid & 63) == 0) red[8 + (tid>>6)] = sm;
        __syncthreads();
        if (tid < 4) red[24+tid] = red[8+2*tid] + red[8+2*tid+1];
        __syncthreads();
    }
    // ans = softmax(A) @ V : V-part with 8-lane p-split; S-part via transposed ST
    if (tid < 480){
        int g = tid >> 3;
        int qi = g / 15, vb = g % 15;
        int pc = tid & 7;
        float ac[8] = {0,0,0,0,0,0,0,0};
        const unsigned short* hb8 = hrb + 8 + vb*8;
        for (int p = pc; p < P_; p += 8){
            float e = elog[qi*P_ + p];
            uint4 hv = *((const uint4*)(hb8 + (size_t)p*128));
            ac[0] += e*BFLO(hv.x); ac[1] += e*BFHI(hv.x);
            ac[2] += e*BFLO(hv.y); ac[3] += e*BFHI(hv.y);
            ac[4] += e*BFLO(hv.z); ac[5] += e*BFHI(hv.z);
            ac[6] += e*BFLO(hv.w); ac[7] += e*BFHI(hv.w);
        }
        #pragma unroll
        for (int j=0;j<8;++j){ ac[j] += __shfl_down(ac[j],4); ac[j] += __shfl_down(ac[j],2); ac[j] += __shfl_down(ac[j],1); }
        if (pc == 0){
            float inv2 = 1.f/red[24+qi];
            #pragma unroll
            for (int j=0;j<8;++j) ansv[qi*184 + vb*8 + j] = ac[j]*inv2;
        }
    }
    {
        int g = tid >> 3;
        int qi = g >> 4, vb4 = g & 15;
        int pc = tid & 7;
        float s0=0.f, s1=0.f, s2v=0.f, s3=0.f;
        const float* S0 = ST + (size_t)(vb4*4)*540;
        for (int p = pc; p < P_; p += 8){
            float e = elog[qi*P_ + p];
            s0 += e*S0[p]; s1 += e*S0[540+p]; s2v += e*S0[1080+p]; s3 += e*S0[1620+p];
        }
        s0 += __shfl_down(s0,4); s0 += __shfl_down(s0,2); s0 += __shfl_down(s0,1);
        s1 += __shfl_down(s1,4); s1 += __shfl_down(s1,2); s1 += __shfl_down(s1,1);
        s2v += __shfl_down(s2v,4); s2v += __shfl_down(s2v,2); s2v += __shfl_down(s2v,1);
        s3 += __shfl_down(s3,4); s3 += __shfl_down(s3,2); s3 += __shfl_down(s3,1);
        if (pc == 0){
            float inv2 = 1.f/red[24+qi];
            ansv[qi*184 + 120 + vb4*4 + 0] = s0*inv2;
            ansv[qi*184 + 120 + vb4*4 + 1] = s1*inv2;
            ansv[qi*184 + 120 + vb4*4 + 2] = s2v*inv2;
            ansv[qi*184 + 120 + vb4*4 + 3] = s3*inv2;
        }
    }
    __syncthreads();
    // hid = relu(ansv @ aw1 + ab1)
    {
        float a0=ab1[tid], a1=0.f, a2=0.f, a3=0.f;
        for (int i8=0;i8<131;++i8){
            uint4 w = *((const uint4*)(pa1 + ((size_t)(i8<<9)+tid)*8));
            float4 av = *((const float4*)(ansv + i8*8));
            float4 av2 = *((const float4*)(ansv + i8*8 + 4));
            a0 += av.x*BFLO(w.x);  a1 += av.y*BFHI(w.x);
            a2 += av.z*BFLO(w.y);  a3 += av.w*BFHI(w.y);
            a0 += av2.x*BFLO(w.z); a1 += av2.y*BFHI(w.z);
            a2 += av2.z*BFLO(w.w); a3 += av2.w*BFHI(w.w);
        }
        hid[tid] = fmaxf((a0+a1)+(a2+a3), 0.f);
    }
    if (tid < 256) hs2[tid] = hs[tid]*m;
    __syncthreads();
    // cis = hid @ aw2 + ab2
    if (tid < 256){
        float a0=ab2[tid],a1=0.f,a2=0.f,a3=0.f;
        for (int i8=0;i8<64;++i8){
            uint4 w = *((const uint4*)(pa2 + ((size_t)(i8<<8)+tid)*8));
            float4 hv = *((const float4*)(hid + i8*8));
            float4 hv2 = *((const float4*)(hid + i8*8 + 4));
            a0 += hv.x*BFLO(w.x);  a1 += hv.y*BFHI(w.x);
            a2 += hv.z*BFLO(w.y);  a3 += hv.w*BFHI(w.y);
            a0 += hv2.x*BFLO(w.z); a1 += hv2.y*BFHI(w.z);
            a2 += hv2.z*BFLO(w.w); a3 += hv2.w*BFHI(w.w);
        }
        cis[tid] = (a0+a1)+(a2+a3);
    }
    __syncthreads();
    // gates = cis @ w_ih^T + hs2 @ w_hh^T + biases
    for (int g = tid; g < 1024; g += 512){
        float a0=bih[g]+bhh[g], a1=0.f, a2=0.f, a3=0.f;
        for (int i8=0;i8<32;++i8){
            uint4 wi = *((const uint4*)(pih + ((size_t)(i8<<10)+g)*8));
            uint4 wh = *((const uint4*)(phh + ((size_t)(i8<<10)+g)*8));
            float4 ca = *((const float4*)(cis + i8*8));
            float4 cb2 = *((const float4*)(cis + i8*8 + 4));
            float4 ha = *((const float4*)(hs2 + i8*8));
            float4 hb2 = *((const float4*)(hs2 + i8*8 + 4));
            a0 += ca.x*BFLO(wi.x) + ha.x*BFLO(wh.x);
            a1 += ca.y*BFHI(wi.x) + ha.y*BFHI(wh.x);
            a2 += ca.z*BFLO(wi.y) + ha.z*BFLO(wh.y);
            a3 += ca.w*BFHI(wi.y) + ha.w*BFHI(wh.y);
            a0 += cb2.x*BFLO(wi.z) + hb2.x*BFLO(wh.z);
            a1 += cb2.y*BFHI(wi.z) + hb2.y*BFHI(wh.z);
            a2 += cb2.z*BFLO(wi.w) + hb2.z*BFLO(wh.w);
            a3 += cb2.w*BFHI(wi.w) + hb2.w*BFHI(wh.w);
        }
        gb[g] = (a0+a1)+(a2+a3);
    }
    __syncthreads();
    if (tid < 256){
        float gi = gb[tid], gf = gb[256+tid], gg = gb[512+tid], go = gb[768+tid];
        float cold = cs[tid]*m;
        float cn = sigm(gf)*cold + sigm(gi)*tanhf(gg);
        float hn = sigm(go)*tanhf(cn);
        csb[b*256+tid] = cn;
        hsb[b*256+tid] = hn;
        outs[(tc*B_+b)*256+tid] = hn;
    }
}

// output heads
__global__ __launch_bounds__(64) void finalk(const float* __restrict__ outs,
                                             const float* __restrict__ pw, const float* __restrict__ pb,
                                             const float* __restrict__ vw, const float* __restrict__ vb,
                                             float* __restrict__ dout){
    int row = blockIdx.x, tid = threadIdx.x;
    __shared__ float os[256];
    __shared__ float lg[NA];
    for (int i=tid; i<256; i+=64) os[i] = outs[row*256+i];
    __syncthreads();
    if (tid < NA){
        float a = pb[tid];
        for (int i=0;i<256;++i) a += os[i]*pw[i*NA+tid];
        lg[tid] = a;
        dout[row*NA + tid] = a;
    } else if (tid == 32){
        float a = vb[0];
        for (int i=0;i<256;++i) a += os[i]*vw[i];
        dout[9216 + row] = a;
    }
    __syncthreads();
    if (tid == 0){
        int am = 0; float bv = lg[0];
        for (int j=1;j<NA;++j) if (lg[j] > bv){ bv = lg[j]; am = j; }
        dout[9728 + row] = (float)am;
    }
}

extern "C" void kernel_launch(void* const* d_in, const int* in_sizes, int n_in,
                              void* d_out, int out_size, void* d_ws, size_t ws_size,
                              hipStream_t stream) {
    const float* frame   = (const float*)d_in[0];
    const unsigned char* done = (const unsigned char*)d_in[1];
    const int*   lact    = (const int*)d_in[2];
    const float* reward  = (const float*)d_in[3];
    const float* core_h0 = (const float*)d_in[4];
    const float* core_c0 = (const float*)d_in[5];
    const float* conv_h0 = (const float*)d_in[6];
    const float* conv_c0 = (const float*)d_in[7];
    const float* cnn_w1  = (const float*)d_in[8];
    const float* cnn_b1  = (const float*)d_in[9];
    const float* cnn_w2  = (const float*)d_in[10];
    const float* cnn_b2  = (const float*)d_in[11];
    const float* lstm_w  = (const float*)d_in[12];
    const float* lstm_b  = (const float*)d_in[13];
    const float* qw1 = (const float*)d_in[14]; const float* qb1 = (const float*)d_in[15];
    const float* qw2 = (const float*)d_in[16]; const float* qb2 = (const float*)d_in[17];
    const float* qw3 = (const float*)d_in[18]; const float* qb3 = (const float*)d_in[19];
    const float* aw1 = (const float*)d_in[20]; const float* ab1 = (const float*)d_in[21];
    const float* aw2 = (const float*)d_in[22]; const float* ab2 = (const float*)d_in[23];
    const float* w_ih = (const float*)d_in[24]; const float* w_hh = (const float*)d_in[25];
    const float* b_ih = (const float*)d_in[26]; const float* b_hh = (const float*)d_in[27];
    const float* pw = (const float*)d_in[28]; const float* pb = (const float*)d_in[29];
    const float* vw = (const float*)d_in[30]; const float* vb = (const float*)d_in[31];

    float* ws = (float*)d_ws;
    float* dout = (float*)d_out;

    // ws layout (float offsets). c1pad is transient: consumed by c2mfma, then the
    // hreA / apack / weight-pack regions are written into that range afterwards.
    unsigned short* xre    = (unsigned short*)ws;                         // 17,694,720 u16
    unsigned short* c1pad  = (unsigned short*)(ws + 10485760);            // 38,535,168 u16 (transient)
    unsigned short* hreA   = (unsigned short*)(ws + 10485760);            // 35,389,440 u16
    unsigned short* apack  = (unsigned short*)(ws + 28180480);            // 884,736 u16
    unsigned short* wpk    = (unsigned short*)(ws + 28966912);            // packed core weights (x8)
    unsigned short* pq1 = wpk;            // 32,768
    unsigned short* pq2 = wpk + 32768;    // 36,864
    unsigned short* pq3 = wpk + 69632;    // 82,944
    unsigned short* pa1 = wpk + 152576;   // 536,576
    unsigned short* pa2 = wpk + 689152;   // 131,072
    unsigned short* pih = wpk + 820224;   // 262,144
    unsigned short* phh = wpk + 1082368;  // 262,144 (ends 1,344,512 u16)
    unsigned short* h0re   = (unsigned short*)(ws + 29753344);            // 1,105,920 u16
    unsigned short* apack2 = (unsigned short*)(ws + 30408704);            // 32,768 u16
    unsigned short* hpl0   = (unsigned short*)(ws + 30425088);            // 1,105,920 u16
    float* hsb   = ws + 31080448;      // 4,096
    float* csb   = ws + 31084544;      // 4,096
    unsigned short* hpl1   = (unsigned short*)(ws + 31100928);            // 1,105,920 u16
    float* ST    = ws + 33460224;      // 34,560
    float* vh    = ws + 34881536;      // 1,105,920
    float* vc    = ws + 35987456;      // 1,105,920
    float* S     = ws + 37093376;      // 34,560
    float* outs  = ws + 37127936;      // 131,072 (ends 37,259,008)

    // zero padded conv1 output planes (interiors overwritten by conv1k)
    hipMemsetAsync(c1pad, 0, (size_t)38535168*2, stream);

    // serial CNN prologue (keeps pipeline L2 clean)
    apack2k<<<128, 256, 0, stream>>>(cnn_w2, apack2);
    conv1k<<<512*26, 256, 0, stream>>>(frame, cnn_w1, cnn_b1, c1pad);
    c2mfma<<<2560, 256, 0, stream>>>(c1pad, apack2, cnn_b2, xre);

    // c1pad dead from here; region reused by the buffers below
    sbasisk<<<135, 256, 0, stream>>>(S, ST);
    apack9k<<<3456, 256, 0, stream>>>(lstm_w, apack);
    packw8k<<<128,  256, 0, stream>>>(qw1, pq1, 256, 128);
    packw8k<<<144,  256, 0, stream>>>(qw2, pq2, 128, 288);
    packw8k<<<324,  256, 0, stream>>>(qw3, pq3, 288, 288);
    packw8k<<<2096, 256, 0, stream>>>(aw1, pa1, 1043, 512);
    packw8k<<<512,  256, 0, stream>>>(aw2, pa2, 512, 256);
    packt8k<<<1024, 256, 0, stream>>>(w_ih, pih, 256, 1024);
    packt8k<<<1024, 256, 0, stream>>>(w_hh, phh, 256, 1024);
    h0rek<<<4320, 256, 0, stream>>>(conv_h0, h0re);
    hipMemcpyAsync(vc,  conv_c0, (size_t)16*128*540*sizeof(float), hipMemcpyDeviceToDevice, stream);
    hipMemcpyAsync(hsb, core_h0, (size_t)16*256*sizeof(float), hipMemcpyDeviceToDevice, stream);
    hipMemcpyAsync(csb, core_c0, (size_t)16*256*sizeof(float), hipMemcpyDeviceToDevice, stream);

    // software-pipelined loop: vis step t || core step t-1 (33 dispatches)
    for (int t = 0; t <= T_; ++t){
        gvpk<<<304, 512, 0, stream>>>(xre,
                                      (t&1)?hpl0:hpl1, (t&1)?hpl1:hpl0, h0re,
                                      apack, lstm_b, done, vh, vc, hreA,
                                      S, ST, pq1,qb1,pq2,qb2,pq3,qb3,
                                      pa1,ab1,pa2,ab2, pih,phh,b_ih,b_hh,
                                      reward, lact, hsb, csb, outs, t);
    }

    finalk<<<512, 64, 0, stream>>>(outs, pw, pb, vw, vb, dout);

    hipMemcpyAsync(dout + 10240,   outs + (size_t)31*B_*256, (size_t)16*256*sizeof(float), hipMemcpyDeviceToDevice, stream);
    hipMemcpyAsync(dout + 14336,   csb, (size_t)16*256*sizeof(float), hipMemcpyDeviceToDevice, stream);
    hipMemcpyAsync(dout + 18432,   vh,  (size_t)16*128*540*sizeof(float), hipMemcpyDeviceToDevice, stream);
    hipMemcpyAsync(dout + 1124352, vc,  (size_t)16*128*540*sizeof(float), hipMemcpyDeviceToDevice, stream);
}